// Round 1
// baseline (227.777 us; speedup 1.0000x reference)
//
#include <hip/hip_runtime.h>

// Involution (B=8, H=W=192, C=64, G=4, K=3, R=4) — fused single kernel.
// Phase A: per-thread pixel computes the 36-entry involution kernel
//          (1x1 conv C->16, BN(inference), ReLU, 1x1 conv 16->36), stores to LDS.
// Phase B: wave remapped to (4 pixels x 16 float4-channel-chunks); 9-tap
//          multiply-reduce with coalesced global x reads + coalesced out stores.
// Memory-bound: ideal traffic ~151 MB -> ~24 us floor @ 6.3 TB/s.

#define B_   8
#define H_   192
#define W_   192
#define C_   64
#define CR_  16
#define TH_  16
#define TW_  16
#define TILES_X (W_/TW_)              // 12
#define TILES_PER_IMG (TILES_X * (H_/TH_))  // 144
#define NBLK (B_ * TILES_PER_IMG)     // 1152

constexpr float BN_EPS = 1e-3f;

__global__ __launch_bounds__(256)
void invol_fused(const float* __restrict__ x,
                 const float* __restrict__ w1,
                 const float* __restrict__ b1,
                 const float* __restrict__ gamma,
                 const float* __restrict__ beta,
                 const float* __restrict__ mean,
                 const float* __restrict__ var,
                 const float* __restrict__ w2,
                 const float* __restrict__ b2,
                 float* __restrict__ out)
{
    // 256 pixels * 9 float4 (36 floats of kern, tap-major, g minor) = 36 KB
    __shared__ float4 s_kern[256 * 9];

    const int bid = blockIdx.x;
    // XCD swizzle: consecutive blockIdx round-robin across 8 XCDs; give each
    // XCD one contiguous image worth of tiles (1152 = 8 * 144) for L2 locality.
    const int tile = (bid & 7) * TILES_PER_IMG + (bid >> 3);
    const int img = tile / TILES_PER_IMG;
    const int tin = tile % TILES_PER_IMG;
    const int th0 = (tin / TILES_X) * TH_;
    const int tw0 = (tin % TILES_X) * TW_;

    const int tid = threadIdx.x;

    // ---------------- Phase A: kernel generation ----------------
    {
        const int r = tid >> 4, cc = tid & 15;
        const int h = th0 + r, w = tw0 + cc;
        const float4* xp = reinterpret_cast<const float4*>(
            x + ((size_t)((img * H_ + h) * W_ + w) << 6));

        float td[CR_];
        #pragma unroll
        for (int d = 0; d < CR_; ++d) td[d] = 0.f;

        // t = x @ w1   (weights: wave-uniform addresses -> scalar loads)
        #pragma unroll
        for (int c4 = 0; c4 < 16; ++c4) {
            const float4 xv = xp[c4];
            const float xs[4] = {xv.x, xv.y, xv.z, xv.w};
            #pragma unroll
            for (int k = 0; k < 4; ++k) {
                const float* wr = w1 + (c4 * 4 + k) * CR_;
                #pragma unroll
                for (int d = 0; d < CR_; ++d)
                    td[d] = fmaf(xs[k], wr[d], td[d]);
            }
        }

        // + b1, BN (inference), ReLU — folded into one affine
        #pragma unroll
        for (int d = 0; d < CR_; ++d) {
            const float a = gamma[d] * rsqrtf(var[d] + BN_EPS);
            const float c = (b1[d] - mean[d]) * a + beta[d];
            td[d] = fmaxf(fmaf(td[d], a, c), 0.f);
        }

        // kern = t @ w2 + b2  (36 outputs, e = tap*4 + g)
        float ke[36];
        #pragma unroll
        for (int e = 0; e < 36; ++e) ke[e] = b2[e];
        #pragma unroll
        for (int d = 0; d < CR_; ++d) {
            const float t = td[d];
            const float* wr = w2 + d * 36;
            #pragma unroll
            for (int e = 0; e < 36; ++e)
                ke[e] = fmaf(t, wr[e], ke[e]);
        }

        // LDS write: stride 36 words (144 B, 16B-aligned) -> conflict-free b128
        float4* skq = &s_kern[tid * 9];
        #pragma unroll
        for (int t9 = 0; t9 < 9; ++t9)
            skq[t9] = make_float4(ke[t9 * 4 + 0], ke[t9 * 4 + 1],
                                  ke[t9 * 4 + 2], ke[t9 * 4 + 3]);
    }

    __syncthreads();

    // ---------------- Phase B: 9-tap multiply-reduce ----------------
    // Wave handles 4 pixels x 16 channel-chunks: lane = ploc*16 + c4i.
    // Channel chunk c4i covers channels 4*c4i..4*c4i+3, whose group indices
    // are exactly g = 0..3 (C reshaped to (C//G, G), G minor) -> kern float4.
    const int lane = tid & 63;
    const int wv   = tid >> 6;       // wave id 0..3
    const int ploc = lane >> 4;      // pixel within quad
    const int c4i  = lane & 15;      // float4 channel chunk

    for (int i = 0; i < 16; ++i) {
        const int q = wv * 64 + i * 4 + ploc;   // pixel 0..255 in tile
        const int r = q >> 4, cc = q & 15;
        const int h = th0 + r, w = tw0 + cc;
        const float4* kq = &s_kern[q * 9];

        float4 acc = make_float4(0.f, 0.f, 0.f, 0.f);
        #pragma unroll
        for (int ti = 0; ti < 3; ++ti) {
            const int hh = h + ti - 1;
            if ((unsigned)hh < (unsigned)H_) {
                #pragma unroll
                for (int tj = 0; tj < 3; ++tj) {
                    const int ww = w + tj - 1;
                    if ((unsigned)ww < (unsigned)W_) {
                        const float4 kv = kq[ti * 3 + tj];
                        const float4 xv = reinterpret_cast<const float4*>(
                            x + ((size_t)((img * H_ + hh) * W_ + ww) << 6))[c4i];
                        acc.x = fmaf(kv.x, xv.x, acc.x);
                        acc.y = fmaf(kv.y, xv.y, acc.y);
                        acc.z = fmaf(kv.z, xv.z, acc.z);
                        acc.w = fmaf(kv.w, xv.w, acc.w);
                    }
                }
            }
        }
        reinterpret_cast<float4*>(
            out + ((size_t)((img * H_ + h) * W_ + w) << 6))[c4i] = acc;
    }
}

extern "C" void kernel_launch(void* const* d_in, const int* in_sizes, int n_in,
                              void* d_out, int out_size, void* d_ws, size_t ws_size,
                              hipStream_t stream) {
    const float* x     = (const float*)d_in[0];
    const float* w1    = (const float*)d_in[1];
    const float* b1    = (const float*)d_in[2];
    const float* gamma = (const float*)d_in[3];
    const float* beta  = (const float*)d_in[4];
    const float* mean  = (const float*)d_in[5];
    const float* var   = (const float*)d_in[6];
    const float* w2    = (const float*)d_in[7];
    const float* b2    = (const float*)d_in[8];
    float* out = (float*)d_out;

    invol_fused<<<dim3(NBLK), dim3(256), 0, stream>>>(
        x, w1, b1, gamma, beta, mean, var, w2, b2, out);
}

// Round 2
// 201.316 us; speedup vs baseline: 1.1314x; 1.1314x over previous
//
#include <hip/hip_runtime.h>

// Involution (B=8, H=W=192, C=64, G=4, K=3, R=4) — fused, round 2.
// R1 post-mortem: latency-bound (21% HBM, 17% VALU, 31% occupancy).
// Changes: 16x8 tile / 128 threads -> 2304 blocks (2x grid), 18 KB LDS
// (8 blocks/CU cap), __launch_bounds__(128,4) for 16 waves/CU, and a
// branchless Phase B (interior fast path + clamp/mask edge path).

#define B_   8
#define H_   192
#define W_   192
#define C_   64
#define CR_  16
#define TH_  8
#define TW_  16
#define TILES_X (W_/TW_)                    // 12
#define TILES_Y (H_/TH_)                    // 24
#define TILES_PER_IMG (TILES_X * TILES_Y)   // 288
#define NBLK (B_ * TILES_PER_IMG)           // 2304
#define NPIX (TH_ * TW_)                    // 128 pixels per block

constexpr float BN_EPS = 1e-3f;

// Phase B inner loop, templated on interior (uniform per block).
template <bool INTERIOR>
__device__ __forceinline__ void phase_b(const float* __restrict__ x,
                                        float* __restrict__ out,
                                        const float4* __restrict__ s_kern,
                                        int img, int th0, int tw0, int tid)
{
    const int c4i  = tid & 15;   // float4 channel chunk (g = 0..3 within it)
    const int prow = tid >> 4;   // 0..7 across both waves; quad-adjacent pixels
    const float* ximg = x + ((size_t)img * H_ * W_ << 6);
    float* oimg = out + ((size_t)img * H_ * W_ << 6);

    #pragma unroll 2
    for (int i = 0; i < 16; ++i) {
        const int q = i * 8 + prow;          // pixel 0..127 in tile
        const int r = q >> 4, cc = q & 15;   // 16-wide rows
        const int h = th0 + r, w = tw0 + cc;
        const float4* kq = &s_kern[q * 9];

        float4 acc = make_float4(0.f, 0.f, 0.f, 0.f);
        #pragma unroll
        for (int ti = 0; ti < 3; ++ti) {
            const int hh = h + ti - 1;
            int hc = hh;
            bool vh = true;
            if (!INTERIOR) {
                vh = (unsigned)hh < (unsigned)H_;
                hc = hh < 0 ? 0 : (hh >= H_ ? H_ - 1 : hh);
            }
            #pragma unroll
            for (int tj = 0; tj < 3; ++tj) {
                const int ww = w + tj - 1;
                int wc = ww;
                bool valid = true;
                if (!INTERIOR) {
                    valid = vh && ((unsigned)ww < (unsigned)W_);
                    wc = ww < 0 ? 0 : (ww >= W_ ? W_ - 1 : ww);
                }
                const float4 xv = reinterpret_cast<const float4*>(
                    ximg + ((size_t)(hc * W_ + wc) << 6))[c4i];
                float4 kv = kq[ti * 3 + tj];
                if (!INTERIOR) {
                    kv.x = valid ? kv.x : 0.f;
                    kv.y = valid ? kv.y : 0.f;
                    kv.z = valid ? kv.z : 0.f;
                    kv.w = valid ? kv.w : 0.f;
                }
                acc.x = fmaf(kv.x, xv.x, acc.x);
                acc.y = fmaf(kv.y, xv.y, acc.y);
                acc.z = fmaf(kv.z, xv.z, acc.z);
                acc.w = fmaf(kv.w, xv.w, acc.w);
            }
        }
        reinterpret_cast<float4*>(oimg + ((size_t)(h * W_ + w) << 6))[c4i] = acc;
    }
}

__global__ __launch_bounds__(128, 4)
void invol_fused(const float* __restrict__ x,
                 const float* __restrict__ w1,
                 const float* __restrict__ b1,
                 const float* __restrict__ gamma,
                 const float* __restrict__ beta,
                 const float* __restrict__ mean,
                 const float* __restrict__ var,
                 const float* __restrict__ w2,
                 const float* __restrict__ b2,
                 float* __restrict__ out)
{
    // 128 pixels * 9 float4 (36 kern floats, tap-major, g minor) = 18 KB
    __shared__ float4 s_kern[NPIX * 9];

    const int bid = blockIdx.x;
    // XCD swizzle: round-robin across 8 XCDs; each XCD owns one image
    // (2304 = 8 * 288) so halo re-reads stay in its own L2.
    const int img = bid & 7;
    const int tin = bid >> 3;
    const int th0 = (tin / TILES_X) * TH_;
    const int tw0 = (tin % TILES_X) * TW_;

    const int tid = threadIdx.x;

    // ---------------- Phase A: kernel generation (1 thread = 1 pixel) -------
    {
        const int r = tid >> 4, cc = tid & 15;
        const int h = th0 + r, w = tw0 + cc;
        const float4* xp = reinterpret_cast<const float4*>(
            x + ((size_t)((img * H_ + h) * W_ + w) << 6));

        float td[CR_];
        #pragma unroll
        for (int d = 0; d < CR_; ++d) td[d] = 0.f;

        // t = x @ w1   (weight addresses wave-uniform -> scalar loads)
        #pragma unroll
        for (int c4 = 0; c4 < 16; ++c4) {
            const float4 xv = xp[c4];
            const float xs[4] = {xv.x, xv.y, xv.z, xv.w};
            #pragma unroll
            for (int k = 0; k < 4; ++k) {
                const float* wr = w1 + (c4 * 4 + k) * CR_;
                #pragma unroll
                for (int d = 0; d < CR_; ++d)
                    td[d] = fmaf(xs[k], wr[d], td[d]);
            }
        }

        // + b1, BN (inference), ReLU — folded affine
        #pragma unroll
        for (int d = 0; d < CR_; ++d) {
            const float a = gamma[d] * rsqrtf(var[d] + BN_EPS);
            const float c = (b1[d] - mean[d]) * a + beta[d];
            td[d] = fmaxf(fmaf(td[d], a, c), 0.f);
        }

        // kern = t @ w2 + b2  (e = tap*4 + g)
        float ke[36];
        #pragma unroll
        for (int e = 0; e < 36; ++e) ke[e] = b2[e];
        #pragma unroll
        for (int d = 0; d < CR_; ++d) {
            const float t = td[d];
            const float* wr = w2 + d * 36;
            #pragma unroll
            for (int e = 0; e < 36; ++e)
                ke[e] = fmaf(t, wr[e], ke[e]);
        }

        // stride 36 words (144 B): lane-quad pixels land on banks 0/4/8/12 —
        // conflict-free b128 writes/reads (verified: SQ_LDS_BANK_CONFLICT=0)
        float4* skq = &s_kern[tid * 9];
        #pragma unroll
        for (int t9 = 0; t9 < 9; ++t9)
            skq[t9] = make_float4(ke[t9 * 4 + 0], ke[t9 * 4 + 1],
                                  ke[t9 * 4 + 2], ke[t9 * 4 + 3]);
    }

    __syncthreads();

    // ---------------- Phase B: 9-tap multiply-reduce ------------------------
    const bool interior = (th0 > 0) && (th0 + TH_ < H_) &&
                          (tw0 > 0) && (tw0 + TW_ < W_);
    if (interior)
        phase_b<true>(x, out, s_kern, img, th0, tw0, tid);
    else
        phase_b<false>(x, out, s_kern, img, th0, tw0, tid);
}

extern "C" void kernel_launch(void* const* d_in, const int* in_sizes, int n_in,
                              void* d_out, int out_size, void* d_ws, size_t ws_size,
                              hipStream_t stream) {
    const float* x     = (const float*)d_in[0];
    const float* w1    = (const float*)d_in[1];
    const float* b1    = (const float*)d_in[2];
    const float* gamma = (const float*)d_in[3];
    const float* beta  = (const float*)d_in[4];
    const float* mean  = (const float*)d_in[5];
    const float* var   = (const float*)d_in[6];
    const float* w2    = (const float*)d_in[7];
    const float* b2    = (const float*)d_in[8];
    float* out = (float*)d_out;

    invol_fused<<<dim3(NBLK), dim3(128), 0, stream>>>(
        x, w1, b1, gamma, beta, mean, var, w2, b2, out);
}